// Round 6
// baseline (1035.835 us; speedup 1.0000x reference)
//
#include <hip/hip_runtime.h>
#include <hip/hip_bf16.h>
#include <stdint.h>

typedef __attribute__((ext_vector_type(8))) short s8v;
typedef __attribute__((ext_vector_type(4))) float f32x4;

__device__ __forceinline__ unsigned short f2bf(float f) {
  unsigned u = __builtin_bit_cast(unsigned, f);
  u += 0x7fffu + ((u >> 16) & 1u);
  return (unsigned short)(u >> 16);
}

__device__ __forceinline__ void gl16(const void* g, void* l) {
  __builtin_amdgcn_global_load_lds(
      (const __attribute__((address_space(1))) unsigned int*)g,
      (__attribute__((address_space(3))) unsigned int*)l,
      16, 0, 0);
}

// ---------------- prep kernels ----------------

__global__ void cast_bf16_k(const float* __restrict__ s, unsigned short* __restrict__ d, int n4) {
  int i = blockIdx.x * blockDim.x + threadIdx.x;
  if (i < n4) {
    float4 v = reinterpret_cast<const float4*>(s)[i];
    ushort4 o;
    o.x = f2bf(v.x); o.y = f2bf(v.y); o.z = f2bf(v.z); o.w = f2bf(v.w);
    reinterpret_cast<ushort4*>(d)[i] = o;
  }
}

// Conv matrix, FRAGMENT-MAJOR:
// MtF[(((j*8+kk)*8+tile)*64 + l15*4 + g8)*8 + e] = Mt[n=j*128+tile*16+l15][k=kk*32+g8*8+e]
__global__ void prep_convF(
    const float* w0, const float* w1, const float* w2, const float* w3,
    const float* w4, const float* w5, const float* w6,
    const float* b0, const float* b1, const float* b2, const float* b3,
    const float* b4, const float* b5, const float* b6,
    unsigned short* __restrict__ MtF, float* __restrict__ cbias)
{
  int n = blockIdx.x * blockDim.x + threadIdx.x;
  if (n >= 3712) return;
  const int j = n >> 7, nn = n & 127, tile = nn >> 4, ln = nn & 15;
  auto put = [&](int k, unsigned short v) {
    int kk = k >> 5, gk = (k >> 3) & 3, e = k & 7;
    MtF[(size_t)((((j * 8 + kk) * 8 + tile) * 64 + ln * 4 + gk) * 8 + e)] = v;
  };
  for (int k = 0; k < 256; ++k) put(k, 0);
  if (n >= 3648) { cbias[n] = 0.f; return; }
  const int khs[7] = {1,2,1,3,1,4,2};
  const int kws[7] = {2,1,3,1,4,1,2};
  const int cs[8]  = {0,768,1536,2048,2560,2816,3072,3648};
  const float* ws[7] = {w0,w1,w2,w3,w4,w5,w6};
  const float* bs[7] = {b0,b1,b2,b3,b4,b5,b6};
  int kern = 6;
  while (n < cs[kern]) --kern;
  const int kh = khs[kern], kw = kws[kern];
  const int ow = 5 - kw, np = (5 - kh) * ow;
  const int r = n - cs[kern];
  const int och = r / np, p = r % np;
  const int oi = p / ow, oj = p % ow;
  const float* w = ws[kern];
  cbias[n] = bs[kern][och];
  for (int c = 0; c < 16; ++c)
    for (int dh = 0; dh < kh; ++dh)
      for (int dw = 0; dw < kw; ++dw)
        put(c * 16 + (oi + dh) * 4 + (oj + dw),
            f2bf(w[((och * 16 + c) * kh + dh) * kw + dw]));
}

// fw0 [512][3648] f32 -> fragment-major bf16, K padded to 3712:
// fwF[(((j*4+kk)*32+tile)*64 + l15*4 + g8)*8 + e] = fw0[n=tile*16+l15][k=j*128+kk*32+g8*8+e]
__global__ void prep_fw0F(const float* __restrict__ fw0, unsigned short* __restrict__ outp) {
  int idx = blockIdx.x * 256 + threadIdx.x;  // 512*3712
  int nrow = idx / 3712;
  int k = idx - nrow * 3712;
  const int j = k >> 7, kk = (k >> 5) & 3, gk = (k >> 3) & 3, e = k & 7;
  const int tile = nrow >> 4, ln = nrow & 15;
  outp[(size_t)((((j * 4 + kk) * 32 + tile) * 64 + ln * 4 + gk) * 8 + e)] =
      (k < 3648) ? f2bf(fw0[nrow * 3648 + k]) : (unsigned short)0;
}

// ---------------- fused conv + FC1 (v6: j-split, ps dbuf, 1 barrier/j) ----------------
// mode 0: j in [j_lo,j_hi), acc starts 0, epilogue stores gacc f32.
// mode 1: acc starts from gacc, epilogue writes h1 = relu(acc+fb0) bf16.
// Per-kernel weight footprint = (j_hi-j_lo)*192KB < 4MB -> L2-resident sweeps.
__global__ __launch_bounds__(512, 4) void fused_conv_fc1(
    const unsigned short* __restrict__ xb,   // [32768][256]
    const unsigned short* __restrict__ MtF,  // fragment-major conv matrix
    const float* __restrict__ cbias,         // [3712]
    const unsigned short* __restrict__ fwF,  // fragment-major fw0
    const float* __restrict__ fb0,           // [512]
    float* __restrict__ gacc,                // [32768][512] f32 handoff
    unsigned short* __restrict__ h1,         // [32768][512]
    int j_lo, int j_hi, int mode)
{
  __shared__ unsigned short xs[64 * 256];      // 32 KB, XOR-swizzled content
  __shared__ unsigned short ps[2][64 * 128];   // 2 x 16 KB, swizzled
  const int tid = threadIdx.x;
  const int lane = tid & 63;
  const int w = tid >> 6;      // 0..7
  const int g8 = lane >> 4;
  const int l15 = lane & 15;
  const int m0 = blockIdx.x * 64;
  const int cwm = w >> 2;      // conv: 0..1 (32 batch rows)
  const int cwn = w & 3;       // conv: 0..3 (32 conv cols)

  // stage xs once (swizzled content via pre-swizzled global col)
  {
    char* dst = (char*)xs + w * 4096 + lane * 16;
#pragma unroll
    for (int i = 0; i < 4; ++i) {
      int c = (w * 4 + i) * 64 + lane;  // 0..2047
      int row = c >> 5, col16 = c & 31;
      gl16(xb + (size_t)(m0 + row) * 256 + (col16 ^ (row & 7)) * 8, dst + i * 1024);
    }
  }

  f32x4 acc[4][4];
  if (mode == 0) {
#pragma unroll
    for (int mi = 0; mi < 4; ++mi)
#pragma unroll
      for (int ni = 0; ni < 4; ++ni)
        acc[mi][ni] = f32x4{0.f, 0.f, 0.f, 0.f};
  } else {
#pragma unroll
    for (int mi = 0; mi < 4; ++mi)
#pragma unroll
      for (int ni = 0; ni < 4; ++ni)
#pragma unroll
        for (int r = 0; r < 4; ++r)
          acc[mi][ni][r] =
              gacc[(size_t)(m0 + mi * 16 + g8 * 4 + r) * 512 + w * 64 + ni * 16 + l15];
  }
  f32x4 accp[2][2];

  auto conv = [&](int jj) {
#pragma unroll
    for (int mi = 0; mi < 2; ++mi)
#pragma unroll
      for (int ni = 0; ni < 2; ++ni)
        accp[mi][ni] = f32x4{0.f, 0.f, 0.f, 0.f};
    const unsigned short* mtj = MtF + (size_t)jj * 32768;
#pragma unroll
    for (int kk = 0; kk < 8; ++kk) {
      s8v xa[2], mb[2];
#pragma unroll
      for (int mi = 0; mi < 2; ++mi) {
        int r = cwm * 32 + mi * 16 + l15;
        xa[mi] = *(const s8v*)((const char*)xs + r * 512 +
                               (((kk * 4 + g8) ^ (r & 7)) << 4));
      }
#pragma unroll
      for (int ni = 0; ni < 2; ++ni)
        mb[ni] = *(const s8v*)(mtj + ((kk * 8 + cwn * 2 + ni) * 64 + l15 * 4 + g8) * 8);
#pragma unroll
      for (int mi = 0; mi < 2; ++mi)
#pragma unroll
        for (int ni = 0; ni < 2; ++ni)
          accp[mi][ni] = __builtin_amdgcn_mfma_f32_16x16x32_bf16(
              xa[mi], mb[ni], accp[mi][ni], 0, 0, 0);
    }
  };

  auto pwrite = [&](int jj) {
    unsigned short* psb = ps[jj & 1];
#pragma unroll
    for (int ni = 0; ni < 2; ++ni) {
      const int pc = cwn * 32 + ni * 16 + l15;
      const float bv = cbias[jj * 128 + pc];
#pragma unroll
      for (int mi = 0; mi < 2; ++mi) {
#pragma unroll
        for (int r = 0; r < 4; ++r) {
          const int pr = cwm * 32 + mi * 16 + g8 * 4 + r;
          float v = accp[mi][ni][r] + bv;
          v = v > 0.f ? v : 0.f;
          *(unsigned short*)((char*)psb + pr * 256 +
                             (((pc >> 3) ^ (pr & 7)) << 4) + (pc & 7) * 2) = f2bf(v);
        }
      }
    }
  };

  __syncthreads();            // xs staged (gl16 drained)
  conv(j_lo);
  pwrite(j_lo);
  __syncthreads();            // ps[j_lo] ready

#pragma unroll 1
  for (int j = j_lo; j < j_hi; ++j) {
    if (j + 1 < j_hi) conv(j + 1);
    // FC1(j): acc += P · fw0_j^T ; wave owns h1 cols w*64..w*64+63
    const unsigned short* psb = ps[j & 1];
    const unsigned short* fwj = fwF + (size_t)j * 65536;
#pragma unroll
    for (int kk = 0; kk < 4; ++kk) {
      s8v pa[4], fwb[4];
#pragma unroll
      for (int mi = 0; mi < 4; ++mi) {
        int r = mi * 16 + l15;
        pa[mi] = *(const s8v*)((const char*)psb + r * 256 +
                               (((kk * 4 + g8) ^ (r & 7)) << 4));
      }
#pragma unroll
      for (int ni = 0; ni < 4; ++ni)
        fwb[ni] = *(const s8v*)(fwj + ((kk * 32 + w * 4 + ni) * 64 + l15 * 4 + g8) * 8);
#pragma unroll
      for (int mi = 0; mi < 4; ++mi)
#pragma unroll
        for (int ni = 0; ni < 4; ++ni)
          acc[mi][ni] = __builtin_amdgcn_mfma_f32_16x16x32_bf16(
              pa[mi], fwb[ni], acc[mi][ni], 0, 0, 0);
    }
    if (j + 1 < j_hi) pwrite(j + 1);
    __syncthreads();          // ps[(j+1)&1] ready; readers of ps[j&1] done
  }

  if (mode == 0) {
#pragma unroll
    for (int mi = 0; mi < 4; ++mi)
#pragma unroll
      for (int ni = 0; ni < 4; ++ni)
#pragma unroll
        for (int r = 0; r < 4; ++r)
          gacc[(size_t)(m0 + mi * 16 + g8 * 4 + r) * 512 + w * 64 + ni * 16 + l15] =
              acc[mi][ni][r];
  } else {
#pragma unroll
    for (int ni = 0; ni < 4; ++ni) {
      const int col = w * 64 + ni * 16 + l15;
      const float bv = fb0[col];
#pragma unroll
      for (int mi = 0; mi < 4; ++mi) {
        const int row = m0 + mi * 16 + g8 * 4;
#pragma unroll
        for (int r = 0; r < 4; ++r) {
          float v = acc[mi][ni][r] + bv;
          v = v > 0.f ? v : 0.f;
          h1[(size_t)(row + r) * 512 + col] = f2bf(v);
        }
      }
    }
  }
}

// ---------------- FC2 (MFMA) + FC3 (fp32 VALU) fused ----------------
__global__ __launch_bounds__(256) void fc23(
    const unsigned short* __restrict__ h1,
    const unsigned short* __restrict__ fw1b,
    const float* __restrict__ fb1,
    const float* __restrict__ fw2,
    const float* __restrict__ fb2,
    float* __restrict__ out)
{
  __shared__ unsigned short As[64 * 64];
  __shared__ unsigned short Bs[128 * 64];
  __shared__ float h2[64][129];
  const int tid = threadIdx.x;
  const int lane = tid & 63;
  const int wave = tid >> 6;
  const int wm = wave >> 1, wn = wave & 1;
  const int m0 = blockIdx.x * 64;

  f32x4 acc[2][4] = {};

  const unsigned short* Ag = h1 + (size_t)(m0 + (lane >> 3)) * 512 + (lane & 7) * 8;
  const unsigned short* Bg = fw1b + (size_t)(lane >> 3) * 512 + (lane & 7) * 8;
  char* Asb = (char*)As + wave * 2048 + lane * 16;
  char* Bsb = (char*)Bs + wave * 4096 + lane * 16;

  for (int k0 = 0; k0 < 512; k0 += 64) {
#pragma unroll
    for (int i = 0; i < 2; ++i)
      gl16(Ag + (size_t)((wave * 2 + i) * 8) * 512 + k0, Asb + i * 1024);
#pragma unroll
    for (int i = 0; i < 4; ++i)
      gl16(Bg + (size_t)((wave * 4 + i) * 8) * 512 + k0, Bsb + i * 1024);
    __syncthreads();
    const int arow = wm * 32 + (lane & 15);
    const int brow = wn * 64 + (lane & 15);
    const int kc = (lane >> 4) * 8;
    s8v af[2][2], bfv[4][2];
#pragma unroll
    for (int mi = 0; mi < 2; ++mi)
#pragma unroll
      for (int kk = 0; kk < 2; ++kk)
        af[mi][kk] = *(const s8v*)(As + (arow + mi * 16) * 64 + kk * 32 + kc);
#pragma unroll
    for (int ni = 0; ni < 4; ++ni)
#pragma unroll
      for (int kk = 0; kk < 2; ++kk)
        bfv[ni][kk] = *(const s8v*)(Bs + (brow + ni * 16) * 64 + kk * 32 + kc);
#pragma unroll
    for (int kk = 0; kk < 2; ++kk)
#pragma unroll
      for (int mi = 0; mi < 2; ++mi)
#pragma unroll
        for (int ni = 0; ni < 4; ++ni)
          acc[mi][ni] = __builtin_amdgcn_mfma_f32_16x16x32_bf16(
              af[mi][kk], bfv[ni][kk], acc[mi][ni], 0, 0, 0);
    __syncthreads();
  }

#pragma unroll
  for (int ni = 0; ni < 4; ++ni) {
    const int col = wn * 64 + ni * 16 + (lane & 15);
    const float bv = fb1[col];
#pragma unroll
    for (int mi = 0; mi < 2; ++mi) {
      const int rl = wm * 32 + mi * 16 + (lane >> 4) * 4;
#pragma unroll
      for (int r = 0; r < 4; ++r) {
        float v = acc[mi][ni][r] + bv;
        h2[rl + r][col] = v > 0.f ? v : 0.f;
      }
    }
  }
  __syncthreads();

  const int r = tid >> 2, j = tid & 3;
  const float* w = fw2 + j * 128;
  float dot = fb2[j];
#pragma unroll 8
  for (int c = 0; c < 128; ++c) dot += h2[r][c] * w[c];
  out[(size_t)(m0 + r) * 4 + j] = dot;
}

// ---------------- launch ----------------

extern "C" void kernel_launch(void* const* d_in, const int* in_sizes, int n_in,
                              void* d_out, int out_size, void* d_ws, size_t ws_size,
                              hipStream_t stream) {
  const float* x = (const float*)d_in[0];
  const float* w[7];
  const float* b[7];
  for (int i = 0; i < 7; ++i) {
    w[i] = (const float*)d_in[1 + 2 * i];
    b[i] = (const float*)d_in[2 + 2 * i];
  }
  const float* fw0 = (const float*)d_in[15];
  const float* fb0 = (const float*)d_in[16];
  const float* fw1 = (const float*)d_in[17];
  const float* fb1 = (const float*)d_in[18];
  const float* fw2 = (const float*)d_in[19];
  const float* fb2 = (const float*)d_in[20];

  char* ws = (char*)d_ws;
  size_t off = 0;
  auto alloc = [&](size_t bytes) {
    void* p = ws + off;
    off += (bytes + 255) & ~(size_t)255;
    return p;
  };
  unsigned short* MtF  = (unsigned short*)alloc((size_t)3712 * 256 * 2);  // 1.9 MB
  float*          cb   = (float*)alloc((size_t)3712 * 4);
  unsigned short* fwF  = (unsigned short*)alloc((size_t)512 * 3712 * 2);  // 3.8 MB
  unsigned short* fw1b = (unsigned short*)alloc((size_t)128 * 512 * 2);
  unsigned short* xb   = (unsigned short*)alloc((size_t)32768 * 256 * 2); // 16.8 MB
  unsigned short* h1   = (unsigned short*)alloc((size_t)32768 * 512 * 2); // 33.6 MB
  float*          gacc = (float*)alloc((size_t)32768 * 512 * 4);          // 67.1 MB
  if (ws_size < off) return;  // needs ~123 MB

  cast_bf16_k<<<8192, 256, 0, stream>>>(x, xb, 2097152);
  cast_bf16_k<<<64, 256, 0, stream>>>(fw1, fw1b, 16384);
  prep_convF<<<15, 256, 0, stream>>>(w[0], w[1], w[2], w[3], w[4], w[5], w[6],
                                     b[0], b[1], b[2], b[3], b[4], b[5], b[6], MtF, cb);
  prep_fw0F<<<7424, 256, 0, stream>>>(fw0, fwF);

  // j-split keeps each kernel's weight footprint < 4MB (per-XCD L2)
  fused_conv_fc1<<<512, 512, 0, stream>>>(xb, MtF, cb, fwF, fb0, gacc, h1, 0, 15, 0);
  fused_conv_fc1<<<512, 512, 0, stream>>>(xb, MtF, cb, fwF, fb0, gacc, h1, 15, 29, 1);
  fc23<<<512, 256, 0, stream>>>(h1, fw1b, fb1, fw2, fb2, (float*)d_out);
}

// Round 7
// 590.309 us; speedup vs baseline: 1.7547x; 1.7547x over previous
//
#include <hip/hip_runtime.h>
#include <hip/hip_bf16.h>
#include <stdint.h>

typedef __attribute__((ext_vector_type(8))) short s8v;
typedef __attribute__((ext_vector_type(4))) float f32x4;

__device__ __forceinline__ unsigned short f2bf(float f) {
  unsigned u = __builtin_bit_cast(unsigned, f);
  u += 0x7fffu + ((u >> 16) & 1u);
  return (unsigned short)(u >> 16);
}

__device__ __forceinline__ void gl16(const void* g, void* l) {
  __builtin_amdgcn_global_load_lds(
      (const __attribute__((address_space(1))) unsigned int*)g,
      (__attribute__((address_space(3))) unsigned int*)l,
      16, 0, 0);
}

// ---------------- prep kernels ----------------

__global__ void cast_bf16_k(const float* __restrict__ s, unsigned short* __restrict__ d, int n4) {
  int i = blockIdx.x * blockDim.x + threadIdx.x;
  if (i < n4) {
    float4 v = reinterpret_cast<const float4*>(s)[i];
    ushort4 o;
    o.x = f2bf(v.x); o.y = f2bf(v.y); o.z = f2bf(v.z); o.w = f2bf(v.w);
    reinterpret_cast<ushort4*>(d)[i] = o;
  }
}

// Conv matrix, FRAGMENT-MAJOR:
// MtF[(((j*8+kk)*8+tile)*64 + l15*4 + g8)*8 + e] = Mt[n=j*128+tile*16+l15][k=kk*32+g8*8+e]
__global__ void prep_convF(
    const float* w0, const float* w1, const float* w2, const float* w3,
    const float* w4, const float* w5, const float* w6,
    const float* b0, const float* b1, const float* b2, const float* b3,
    const float* b4, const float* b5, const float* b6,
    unsigned short* __restrict__ MtF, float* __restrict__ cbias)
{
  int n = blockIdx.x * blockDim.x + threadIdx.x;
  if (n >= 3712) return;
  const int j = n >> 7, nn = n & 127, tile = nn >> 4, ln = nn & 15;
  auto put = [&](int k, unsigned short v) {
    int kk = k >> 5, gk = (k >> 3) & 3, e = k & 7;
    MtF[(size_t)((((j * 8 + kk) * 8 + tile) * 64 + ln * 4 + gk) * 8 + e)] = v;
  };
  for (int k = 0; k < 256; ++k) put(k, 0);
  if (n >= 3648) { cbias[n] = 0.f; return; }
  const int khs[7] = {1,2,1,3,1,4,2};
  const int kws[7] = {2,1,3,1,4,1,2};
  const int cs[8]  = {0,768,1536,2048,2560,2816,3072,3648};
  const float* ws[7] = {w0,w1,w2,w3,w4,w5,w6};
  const float* bs[7] = {b0,b1,b2,b3,b4,b5,b6};
  int kern = 6;
  while (n < cs[kern]) --kern;
  const int kh = khs[kern], kw = kws[kern];
  const int ow = 5 - kw, np = (5 - kh) * ow;
  const int r = n - cs[kern];
  const int och = r / np, p = r % np;
  const int oi = p / ow, oj = p % ow;
  const float* w = ws[kern];
  cbias[n] = bs[kern][och];
  for (int c = 0; c < 16; ++c)
    for (int dh = 0; dh < kh; ++dh)
      for (int dw = 0; dw < kw; ++dw)
        put(c * 16 + (oi + dh) * 4 + (oj + dw),
            f2bf(w[((och * 16 + c) * kh + dh) * kw + dw]));
}

// fw0 [512][3648] f32 -> fragment-major bf16, K padded to 3712:
// fwF[(((j*4+kk)*32+tile)*64 + l15*4 + g8)*8 + e] = fw0[n=tile*16+l15][k=j*128+kk*32+g8*8+e]
__global__ void prep_fw0F(const float* __restrict__ fw0, unsigned short* __restrict__ outp) {
  int idx = blockIdx.x * 256 + threadIdx.x;  // 512*3712
  int nrow = idx / 3712;
  int k = idx - nrow * 3712;
  const int j = k >> 7, kk = (k >> 5) & 3, gk = (k >> 3) & 3, e = k & 7;
  const int tile = nrow >> 4, ln = nrow & 15;
  outp[(size_t)((((j * 4 + kk) * 32 + tile) * 64 + ln * 4 + gk) * 8 + e)] =
      (k < 3648) ? f2bf(fw0[nrow * 3648 + k]) : (unsigned short)0;
}

// ---------------- fused conv + FC1 (v7: 16 waves, 32 acc/thread, no spill) ----------------
// 64 batch rows per block, 1024 threads. MODE 0: j[j_lo,j_hi) -> gacc (nt).
// MODE 1: acc from gacc (nt), epilogue h1 = relu(acc+fb0).
// Weights read as coalesced 1KB/wave fragment blocks straight from L2.
template <int MODE>
__global__ __launch_bounds__(1024, 4) void fused_conv_fc1(
    const unsigned short* __restrict__ xb,   // [32768][256]
    const unsigned short* __restrict__ MtF,  // fragment-major conv matrix
    const float* __restrict__ cbias,         // [3712]
    const unsigned short* __restrict__ fwF,  // fragment-major fw0
    const float* __restrict__ fb0,           // [512]
    float* __restrict__ gacc,                // [32768][512] f32 handoff
    unsigned short* __restrict__ h1,         // [32768][512]
    int j_lo, int j_hi)
{
  __shared__ unsigned short xs[64 * 256];      // 32 KB, XOR-swizzled content
  __shared__ unsigned short ps[2][64 * 128];   // 2 x 16 KB, swizzled
  const int tid = threadIdx.x;
  const int lane = tid & 63;
  const int w = tid >> 6;      // 0..15
  const int g8 = lane >> 4;
  const int l15 = lane & 15;
  const int m0 = blockIdx.x * 64;
  const int wm4 = w >> 2;      // conv: row group (0..3) -> rows wm4*16
  const int cn4 = w & 3;       // conv: col group (0..3) -> cols cn4*32

  // stage xs once (swizzled content via pre-swizzled global col); 2 gl16/thread
  {
    char* dst = (char*)xs + tid * 16;
#pragma unroll
    for (int i = 0; i < 2; ++i) {
      int c = i * 1024 + tid;            // 0..2047
      int row = c >> 5, col16 = c & 31;
      gl16(xb + (size_t)(m0 + row) * 256 + (col16 ^ (row & 7)) * 8,
           dst + i * 16384);
    }
  }

  f32x4 acc[4][2];   // rows mi*16, cols w*32 + ni*16
  if (MODE == 0) {
#pragma unroll
    for (int mi = 0; mi < 4; ++mi)
#pragma unroll
      for (int ni = 0; ni < 2; ++ni)
        acc[mi][ni] = f32x4{0.f, 0.f, 0.f, 0.f};
  } else {
#pragma unroll
    for (int mi = 0; mi < 4; ++mi)
#pragma unroll
      for (int ni = 0; ni < 2; ++ni)
#pragma unroll
        for (int r = 0; r < 4; ++r)
          acc[mi][ni][r] = __builtin_nontemporal_load(
              gacc + (size_t)(m0 + mi * 16 + g8 * 4 + r) * 512 + w * 32 + ni * 16 + l15);
  }
  f32x4 accp[2];     // conv: rows wm4*16, cols cn4*32 + ni*16

  auto conv = [&](int jj) {
#pragma unroll
    for (int ni = 0; ni < 2; ++ni)
      accp[ni] = f32x4{0.f, 0.f, 0.f, 0.f};
    const unsigned short* mtj = MtF + (size_t)jj * 32768;
#pragma unroll
    for (int kk = 0; kk < 8; ++kk) {
      const int r = wm4 * 16 + l15;
      s8v xa = *(const s8v*)((const char*)xs + r * 512 +
                             (((kk * 4 + g8) ^ (r & 7)) << 4));
      s8v mb[2];
#pragma unroll
      for (int ni = 0; ni < 2; ++ni)
        mb[ni] = *(const s8v*)(mtj + ((kk * 8 + cn4 * 2 + ni) * 64 + l15 * 4 + g8) * 8);
#pragma unroll
      for (int ni = 0; ni < 2; ++ni)
        accp[ni] = __builtin_amdgcn_mfma_f32_16x16x32_bf16(xa, mb[ni], accp[ni], 0, 0, 0);
    }
  };

  auto pwrite = [&](int jj) {
    unsigned short* psb = ps[jj & 1];
#pragma unroll
    for (int ni = 0; ni < 2; ++ni) {
      const int pc = cn4 * 32 + ni * 16 + l15;
      const float bv = cbias[jj * 128 + pc];
#pragma unroll
      for (int r = 0; r < 4; ++r) {
        const int pr = wm4 * 16 + g8 * 4 + r;
        float v = accp[ni][r] + bv;
        v = v > 0.f ? v : 0.f;
        *(unsigned short*)((char*)psb + pr * 256 +
                           (((pc >> 3) ^ (pr & 7)) << 4) + (pc & 7) * 2) = f2bf(v);
      }
    }
  };

  __syncthreads();            // xs staged (gl16 drained by barrier)
  conv(j_lo);
  pwrite(j_lo);
  __syncthreads();            // ps[j_lo&1] ready

#pragma unroll 1
  for (int j = j_lo; j < j_hi; ++j) {
    if (j + 1 < j_hi) conv(j + 1);
    // FC1(j): acc += P · fw0_j^T ; wave owns h1 cols w*32..w*32+31
    const unsigned short* psb = ps[j & 1];
    const unsigned short* fwj = fwF + (size_t)j * 65536;
#pragma unroll
    for (int kk = 0; kk < 4; ++kk) {
      s8v pa[4], fwb[2];
#pragma unroll
      for (int mi = 0; mi < 4; ++mi) {
        int r = mi * 16 + l15;
        pa[mi] = *(const s8v*)((const char*)psb + r * 256 +
                               (((kk * 4 + g8) ^ (r & 7)) << 4));
      }
#pragma unroll
      for (int ni = 0; ni < 2; ++ni)
        fwb[ni] = *(const s8v*)(fwj + ((kk * 32 + w * 2 + ni) * 64 + l15 * 4 + g8) * 8);
#pragma unroll
      for (int mi = 0; mi < 4; ++mi)
#pragma unroll
        for (int ni = 0; ni < 2; ++ni)
          acc[mi][ni] = __builtin_amdgcn_mfma_f32_16x16x32_bf16(
              pa[mi], fwb[ni], acc[mi][ni], 0, 0, 0);
    }
    if (j + 1 < j_hi) pwrite(j + 1);
    __syncthreads();          // ps[(j+1)&1] ready; readers of ps[j&1] done
  }

  if (MODE == 0) {
#pragma unroll
    for (int mi = 0; mi < 4; ++mi)
#pragma unroll
      for (int ni = 0; ni < 2; ++ni)
#pragma unroll
        for (int r = 0; r < 4; ++r)
          __builtin_nontemporal_store(
              acc[mi][ni][r],
              gacc + (size_t)(m0 + mi * 16 + g8 * 4 + r) * 512 + w * 32 + ni * 16 + l15);
  } else {
#pragma unroll
    for (int ni = 0; ni < 2; ++ni) {
      const int col = w * 32 + ni * 16 + l15;
      const float bv = fb0[col];
#pragma unroll
      for (int mi = 0; mi < 4; ++mi) {
        const int row = m0 + mi * 16 + g8 * 4;
#pragma unroll
        for (int r = 0; r < 4; ++r) {
          float v = acc[mi][ni][r] + bv;
          v = v > 0.f ? v : 0.f;
          h1[(size_t)(row + r) * 512 + col] = f2bf(v);
        }
      }
    }
  }
}

// ---------------- FC2 (MFMA) + FC3 (fp32 VALU) fused ----------------
__global__ __launch_bounds__(256) void fc23(
    const unsigned short* __restrict__ h1,
    const unsigned short* __restrict__ fw1b,
    const float* __restrict__ fb1,
    const float* __restrict__ fw2,
    const float* __restrict__ fb2,
    float* __restrict__ out)
{
  __shared__ unsigned short As[64 * 64];
  __shared__ unsigned short Bs[128 * 64];
  __shared__ float h2[64][129];
  const int tid = threadIdx.x;
  const int lane = tid & 63;
  const int wave = tid >> 6;
  const int wm = wave >> 1, wn = wave & 1;
  const int m0 = blockIdx.x * 64;

  f32x4 acc[2][4] = {};

  const unsigned short* Ag = h1 + (size_t)(m0 + (lane >> 3)) * 512 + (lane & 7) * 8;
  const unsigned short* Bg = fw1b + (size_t)(lane >> 3) * 512 + (lane & 7) * 8;
  char* Asb = (char*)As + wave * 2048 + lane * 16;
  char* Bsb = (char*)Bs + wave * 4096 + lane * 16;

  for (int k0 = 0; k0 < 512; k0 += 64) {
#pragma unroll
    for (int i = 0; i < 2; ++i)
      gl16(Ag + (size_t)((wave * 2 + i) * 8) * 512 + k0, Asb + i * 1024);
#pragma unroll
    for (int i = 0; i < 4; ++i)
      gl16(Bg + (size_t)((wave * 4 + i) * 8) * 512 + k0, Bsb + i * 1024);
    __syncthreads();
    const int arow = wm * 32 + (lane & 15);
    const int brow = wn * 64 + (lane & 15);
    const int kc = (lane >> 4) * 8;
    s8v af[2][2], bfv[4][2];
#pragma unroll
    for (int mi = 0; mi < 2; ++mi)
#pragma unroll
      for (int kk = 0; kk < 2; ++kk)
        af[mi][kk] = *(const s8v*)(As + (arow + mi * 16) * 64 + kk * 32 + kc);
#pragma unroll
    for (int ni = 0; ni < 4; ++ni)
#pragma unroll
      for (int kk = 0; kk < 2; ++kk)
        bfv[ni][kk] = *(const s8v*)(Bs + (brow + ni * 16) * 64 + kk * 32 + kc);
#pragma unroll
    for (int kk = 0; kk < 2; ++kk)
#pragma unroll
      for (int mi = 0; mi < 2; ++mi)
#pragma unroll
        for (int ni = 0; ni < 4; ++ni)
          acc[mi][ni] = __builtin_amdgcn_mfma_f32_16x16x32_bf16(
              af[mi][kk], bfv[ni][kk], acc[mi][ni], 0, 0, 0);
    __syncthreads();
  }

#pragma unroll
  for (int ni = 0; ni < 4; ++ni) {
    const int col = wn * 64 + ni * 16 + (lane & 15);
    const float bv = fb1[col];
#pragma unroll
    for (int mi = 0; mi < 2; ++mi) {
      const int rl = wm * 32 + mi * 16 + (lane >> 4) * 4;
#pragma unroll
      for (int r = 0; r < 4; ++r) {
        float v = acc[mi][ni][r] + bv;
        h2[rl + r][col] = v > 0.f ? v : 0.f;
      }
    }
  }
  __syncthreads();

  const int r = tid >> 2, j = tid & 3;
  const float* w = fw2 + j * 128;
  float dot = fb2[j];
#pragma unroll 8
  for (int c = 0; c < 128; ++c) dot += h2[r][c] * w[c];
  out[(size_t)(m0 + r) * 4 + j] = dot;
}

// ---------------- launch ----------------

extern "C" void kernel_launch(void* const* d_in, const int* in_sizes, int n_in,
                              void* d_out, int out_size, void* d_ws, size_t ws_size,
                              hipStream_t stream) {
  const float* x = (const float*)d_in[0];
  const float* w[7];
  const float* b[7];
  for (int i = 0; i < 7; ++i) {
    w[i] = (const float*)d_in[1 + 2 * i];
    b[i] = (const float*)d_in[2 + 2 * i];
  }
  const float* fw0 = (const float*)d_in[15];
  const float* fb0 = (const float*)d_in[16];
  const float* fw1 = (const float*)d_in[17];
  const float* fb1 = (const float*)d_in[18];
  const float* fw2 = (const float*)d_in[19];
  const float* fb2 = (const float*)d_in[20];

  char* ws = (char*)d_ws;
  size_t off = 0;
  auto alloc = [&](size_t bytes) {
    void* p = ws + off;
    off += (bytes + 255) & ~(size_t)255;
    return p;
  };
  unsigned short* MtF  = (unsigned short*)alloc((size_t)3712 * 256 * 2);  // 1.9 MB
  float*          cb   = (float*)alloc((size_t)3712 * 4);
  unsigned short* fwF  = (unsigned short*)alloc((size_t)512 * 3712 * 2);  // 3.8 MB
  unsigned short* fw1b = (unsigned short*)alloc((size_t)128 * 512 * 2);
  unsigned short* xb   = (unsigned short*)alloc((size_t)32768 * 256 * 2); // 16.8 MB
  unsigned short* h1   = (unsigned short*)alloc((size_t)32768 * 512 * 2); // 33.6 MB
  float*          gacc = (float*)alloc((size_t)32768 * 512 * 4);          // 67.1 MB
  if (ws_size < off) return;  // needs ~123 MB

  cast_bf16_k<<<8192, 256, 0, stream>>>(x, xb, 2097152);
  cast_bf16_k<<<64, 256, 0, stream>>>(fw1, fw1b, 16384);
  prep_convF<<<15, 256, 0, stream>>>(w[0], w[1], w[2], w[3], w[4], w[5], w[6],
                                     b[0], b[1], b[2], b[3], b[4], b[5], b[6], MtF, cb);
  prep_fw0F<<<7424, 256, 0, stream>>>(fw0, fwF);

  // j-split keeps each kernel's weight footprint < 4MB (per-XCD L2);
  // 16-wave blocks keep per-thread regs ~100 < 128 cap (no spill).
  fused_conv_fc1<0><<<512, 1024, 0, stream>>>(xb, MtF, cb, fwF, fb0, gacc, h1, 0, 15);
  fused_conv_fc1<1><<<512, 1024, 0, stream>>>(xb, MtF, cb, fwF, fb0, gacc, h1, 15, 29);
  fc23<<<512, 256, 0, stream>>>(h1, fw1b, fb1, fw2, fb2, (float*)d_out);
}